// Round 5
// baseline (16425.497 us; speedup 1.0000x reference)
//
#include <hip/hip_runtime.h>
#include <math.h>

#define Gz   250
#define NTz  512
#define Bz   32
#define Hz   512
#define Vz   32000
#define Tz   128
#define VBz  128
#define BHz  (Bz*Hz)
#define LBHz (2*BHz)
#define BTVz ((size_t)Bz*(size_t)Tz*(size_t)Vz)

// workspace byte offsets
#define WS_BAR  0         // unsigned[1024]: arrival flags [0..249], mirrors at 256+g*64
#define WS_ASUM 4096      // float[64][32]
#define WS_AMAX 12288     // ull[64][32]
#define WS_H    28672     // float[2 layer][32][512] (single buffer)

// LDS byte offsets (dynamic)
#define L_HSA    0         // float[32][512] swizzled: tile_L0 (written P2, read P1(t+1))
#define L_HSB    65536     // float[32][512] swizzled: tile_L1 (written P3, read P2(t+1))
#define L_LOGITS 131072    // float[32*129]
#define L_SPART  131072    // overlay: float[16*32*8] (clobbers logits AFTER write_logp)
#define L_PMAX   147584    // ull[16*32]
#define L_PSUM   151680    // float[16*32]
#define L_REDM   153728    // ull[8*32]
#define L_REDS   155776    // float[8*32]
#define L_BIAS   156800    // float[16]
#define L_LOGZ   156864    // float[32]
#define L_TOK    156992    // int[32]
#define L_C      157120    // float[2][4][32]
#define L_TOTAL  158144

typedef unsigned long long ull;
typedef float f32x4 __attribute__((ext_vector_type(4)));

__device__ __forceinline__ float sigmf(float x) { return 1.0f / (1.0f + expf(-x)); }

__device__ __forceinline__ ull bp8(const float* p) {   // coherent 8B load (MALL)
  return __hip_atomic_load((const ull*)p, __ATOMIC_RELAXED, __HIP_MEMORY_SCOPE_AGENT);
}
__device__ __forceinline__ void cstore(float* p, float v) {  // write-through 4B store
  __hip_atomic_store(p, v, __ATOMIC_RELAXED, __HIP_MEMORY_SCOPE_AGENT);
}
__device__ __forceinline__ ull packlm(float x, int v) {
  unsigned u = __float_as_uint(x);
  u = (u & 0x80000000u) ? ~u : (u | 0x80000000u);
  return ((ull)u << 32) | (unsigned)(Vz - 1 - v);   // lower v wins ties (np.argmax first-max)
}
// swizzled float index into [32][512] LDS tile
__device__ __forceinline__ int hoff(int b, int k) { return (b << 9) + (k ^ ((b & 15) << 2)); }

// Flag-based grid barrier: per-block arrival slots (no RMW, no shared hot line),
// block 0 wave 0 aggregates, publishes generation to 8 mirror lines.
__device__ __forceinline__ void grid_barrier(unsigned* bar, int bid, unsigned target) {
  __syncthreads();
  const int tid = threadIdx.x;
  if (tid == 0)
    __hip_atomic_store(&bar[bid], target, __ATOMIC_RELEASE, __HIP_MEMORY_SCOPE_AGENT);
  if (bid == 0) {
    if (tid < 64) {
      const int base = tid << 2;
      for (;;) {
        ull a  = __hip_atomic_load((const ull*)&bar[base],     __ATOMIC_RELAXED, __HIP_MEMORY_SCOPE_AGENT);
        ull b2 = __hip_atomic_load((const ull*)&bar[base + 2], __ATOMIC_RELAXED, __HIP_MEMORY_SCOPE_AGENT);
        bool ok = ((base + 0 >= Gz) || ((unsigned)a          >= target))
               && ((base + 1 >= Gz) || ((unsigned)(a  >> 32) >= target))
               && ((base + 2 >= Gz) || ((unsigned)b2         >= target))
               && ((base + 3 >= Gz) || ((unsigned)(b2 >> 32) >= target));
        if (__all(ok)) break;
        __builtin_amdgcn_s_sleep(1);
      }
      if (tid < 8)
        __hip_atomic_store(&bar[256 + (tid << 6)], target, __ATOMIC_RELEASE, __HIP_MEMORY_SCOPE_AGENT);
    }
  } else if (tid == 0) {
    const unsigned* mir = &bar[256 + ((bid & 7) << 6)];
    while (__hip_atomic_load(mir, __ATOMIC_RELAXED, __HIP_MEMORY_SCOPE_AGENT) < target)
      __builtin_amdgcn_s_sleep(2);
  }
  __syncthreads();
}

// stage [32][512] floats from coherent global into swizzled LDS tile (coalesced 8B loads)
__device__ __forceinline__ void stage_rows(const float* __restrict__ src, float* lds, int tid) {
  #pragma unroll
  for (int it = 0; it < 16; ++it) {
    int f = (it * NTz + tid) << 1;
    int b = f >> 9, k = f & 511;
    ull v = bp8(src + f);
    *(ull*)(lds + hoff(b, k)) = v;
  }
}

// one LSTM layer: 512 threads = 2 rowgroups x 8 kq x 32 b. Each thread: 8 gate-rows
// over a 64-wide k slice. x/h from swizzled LDS (or emb), W normal cached loads.
template<bool X_FROM_EMB>
__device__ __forceinline__ void lstm_phase(
    int tid, int hblk,
    const float* __restrict__ emb, const int* s_tok_,
    const float* xlds, const float* hlds,
    const float* __restrict__ Wih, const float* __restrict__ Whh,
    const float* __restrict__ bih, const float* __restrict__ bhh,
    float* s_part_, float* s_bias_, float* c_l,
    float* hdst)
{
  if (tid < 16) {
    int gate = tid >> 2, hl = tid & 3;
    int j = gate * Hz + (hblk << 2) + hl;
    s_bias_[tid] = bih[j] + bhh[j];
  }
  const int b = tid & 31, kq = (tid >> 5) & 7, rp = tid >> 8;
  const int k0 = kq * 64;
  const int swz = (b & 15) << 2;

  const float* wiP[8]; const float* whP[8];
  #pragma unroll
  for (int r = 0; r < 8; ++r) {
    int row = rp * 8 + r; int gate = row >> 2, hl = row & 3;
    size_t j = (size_t)(gate * Hz + (hblk << 2) + hl) * Hz + k0;
    wiP[r] = Wih + j; whP[r] = Whh + j;
  }
  const float* xbase; const float* hbase = hlds + (b << 9);
  if (X_FROM_EMB) xbase = emb + (size_t)s_tok_[b] * Hz + k0;
  else            xbase = xlds + (b << 9);

  float acc[8];
  #pragma unroll
  for (int r = 0; r < 8; ++r) acc[r] = 0.f;

  #pragma unroll 2
  for (int c = 0; c < 64; c += 4) {
    float x0, x1, x2, x3;
    if (X_FROM_EMB) {
      float4 xv = *(const float4*)(xbase + c);
      x0 = fmaxf(xv.x, 0.f); x1 = fmaxf(xv.y, 0.f);
      x2 = fmaxf(xv.z, 0.f); x3 = fmaxf(xv.w, 0.f);
    } else {
      float4 xv = *(const float4*)(xbase + ((k0 + c) ^ swz));
      x0 = xv.x; x1 = xv.y; x2 = xv.z; x3 = xv.w;
    }
    float4 hv = *(const float4*)(hbase + ((k0 + c) ^ swz));
    #pragma unroll
    for (int r = 0; r < 8; ++r) {
      float4 wiv = *(const float4*)(wiP[r] + c);
      float4 whv = *(const float4*)(whP[r] + c);
      acc[r] += x0 * wiv.x + x1 * wiv.y + x2 * wiv.z + x3 * wiv.w
              + hv.x * whv.x + hv.y * whv.y + hv.z * whv.z + hv.w * whv.w;
    }
  }
  #pragma unroll
  for (int r = 0; r < 8; ++r)
    s_part_[((rp * 8 + r) * 32 + b) * 8 + kq] = acc[r];
  __syncthreads();
  {
    int row = tid >> 5, bb = tid & 31;
    float s = s_bias_[row];
    #pragma unroll
    for (int q = 0; q < 8; ++q) s += s_part_[(row * 32 + bb) * 8 + q];
    s_part_[(row * 32 + bb) * 8] = s;
  }
  __syncthreads();
  if (tid < 128) {
    int hl = tid >> 5, bb = tid & 31;
    float gi = s_part_[((0 * 4 + hl) * 32 + bb) * 8];
    float gf = s_part_[((1 * 4 + hl) * 32 + bb) * 8];
    float gg = s_part_[((2 * 4 + hl) * 32 + bb) * 8];
    float go = s_part_[((3 * 4 + hl) * 32 + bb) * 8];
    float c_old = c_l[hl * 32 + bb];
    float cn = sigmf(gf) * c_old + sigmf(gi) * tanhf(gg);
    c_l[hl * 32 + bb] = cn;
    cstore(hdst + bb * Hz + (hblk << 2) + hl, sigmf(go) * tanhf(cn));
  }
}

__device__ __forceinline__ void tok_reduce(int tid, float* acc_sum, ull* acc_max,
                                           float* redS, ull* redM, float* logZ, int* tok) {
  if (tid < 256) {
    int b = tid & 31, g = tid >> 5;
    float s = 0.f; ull m = 0ull;
    #pragma unroll
    for (int u = 0; u < 8; ++u) {
      int bk = g * 8 + u;
      s += __hip_atomic_load(&acc_sum[bk * Bz + b], __ATOMIC_RELAXED, __HIP_MEMORY_SCOPE_AGENT);
      ull x = __hip_atomic_load(&acc_max[bk * Bz + b], __ATOMIC_RELAXED, __HIP_MEMORY_SCOPE_AGENT);
      m = x > m ? x : m;
    }
    redS[g * Bz + b] = s; redM[g * Bz + b] = m;
  }
  __syncthreads();
  if (tid < 32) {
    float s = 0.f; ull m = 0ull;
    #pragma unroll
    for (int g = 0; g < 8; ++g) {
      s += redS[g * Bz + tid];
      ull x = redM[g * Bz + tid]; m = x > m ? x : m;
    }
    logZ[tid] = logf(s);
    tok[tid] = (Vz - 1) - (int)(unsigned)(m & 0xFFFFFFFFull);
  }
  __syncthreads();
}

__device__ __forceinline__ void write_logp(int tid, int v0, int tstep,
                                           const float* logits_, const float* logZ_, float* out) {
  #pragma unroll
  for (int i = 0; i < 2; ++i) {
    int pos = ((i * NTz) + tid) * 4;      // 0..4095
    int b = pos >> 7, v = pos & 127;
    float lz = logZ_[b];
    f32x4 rr;
    rr.x = logits_[b * 129 + v]     - lz;
    rr.y = logits_[b * 129 + v + 1] - lz;
    rr.z = logits_[b * 129 + v + 2] - lz;
    rr.w = logits_[b * 129 + v + 3] - lz;
    __builtin_nontemporal_store(rr,
        (f32x4*)(out + (size_t)b * ((size_t)Tz * Vz) + (size_t)tstep * Vz + v0 + v));
  }
}

__global__ void rnn_init(const float* __restrict__ enc, float* __restrict__ ws) {
  int i = blockIdx.x * blockDim.x + threadIdx.x;   // 32768 threads
  float* hs = (float*)((char*)ws + WS_H);
  if (i < LBHz) hs[i] = enc[i];
  if (i < 2048) {
    ((float*)((char*)ws + WS_ASUM))[i] = 0.f;
    ((ull*)((char*)ws + WS_AMAX))[i] = 0ull;
  }
  if (i < 1024) ((unsigned*)ws)[i] = 0u;
}

__global__ __launch_bounds__(NTz, 2) void rnn_decode(
    const float* __restrict__ emb,  const float* __restrict__ Wih,
    const float* __restrict__ Whh,  const float* __restrict__ bih,
    const float* __restrict__ bhh,  const float* __restrict__ Wout,
    const float* __restrict__ bout, float* __restrict__ out,
    float* __restrict__ ws)
{
  extern __shared__ char smem[];
  const int tid = threadIdx.x;
  const int bid = blockIdx.x;

  unsigned* bar  = (unsigned*)ws;
  float* acc_sum = (float*)((char*)ws + WS_ASUM);
  ull*   acc_max = (ull*)((char*)ws + WS_AMAX);
  float* hbufs   = (float*)((char*)ws + WS_H);

  float* hsA    = (float*)(smem + L_HSA);
  float* hsB    = (float*)(smem + L_HSB);
  float* logits = (float*)(smem + L_LOGITS);
  float* s_part = (float*)(smem + L_SPART);
  ull*   pmax   = (ull*)(smem + L_PMAX);
  float* psum   = (float*)(smem + L_PSUM);
  ull*   redM   = (ull*)(smem + L_REDM);
  float* redS   = (float*)(smem + L_REDS);
  float* s_bias = (float*)(smem + L_BIAS);
  float* s_logZ = (float*)(smem + L_LOGZ);
  int*   s_tok  = (int*)(smem + L_TOK);
  float* s_c    = (float*)(smem + L_C);

  const int v0 = bid * VBz;
  if (tid < 256) s_c[tid] = 0.f;

  //---- one-time: this block's W_out slice into registers -------------------
  // thread (vg,kq): rows v0+vg*4+r (r<4); k-chunk kq*32..+31 as 8 rotated float4
  const int vg = tid >> 4, kq = tid & 15;
  f32x4 w4[4][8];
  float b_r[4];
  #pragma unroll
  for (int r = 0; r < 4; ++r) {
    const float* wrow = Wout + (size_t)(v0 + (vg << 2) + r) * Hz + (kq << 5);
    #pragma unroll
    for (int j = 0; j < 8; ++j) {
      const int off = ((j + kq) & 7) << 2;
      w4[r][j] = *(const f32x4*)(wrow + off);
    }
    b_r[r] = bout[v0 + (vg << 2) + r];
  }

  //---- pre-loop: stage initial h tiles (LSTM blocks only) ------------------
  if (bid < 128) {
    stage_rows(hbufs, hsA, tid);           // h0 layer0
    stage_rows(hbufs + BHz, hsB, tid);     // h0 layer1
  }
  __syncthreads();

  unsigned bcnt = 0;

  for (int t = 0; t < Tz; ++t) {
    //---- P1: token decode; logp(t-1); LSTM layer 0 (h from resident hsA) ----
    if (t == 0) {
      if (tid < 32) s_tok[tid] = 1;   // SOS
      __syncthreads();
    } else {
      tok_reduce(tid, acc_sum, acc_max, redS, redM, s_logZ, s_tok);
      write_logp(tid, v0, t - 1, logits, s_logZ, out);
      __syncthreads();
    }
    if (bid < 128)
      lstm_phase<true>(tid, bid, emb, s_tok, nullptr, hsA,
                       Wih, Whh, bih, bhh, s_part, s_bias, s_c, hbufs);
    grid_barrier(bar, bid, ++bcnt);

    //---- P2: LSTM layer 1 (x = staged fresh h_L0, h = resident hsB) --------
    if (bid < 128) {
      stage_rows(hbufs, hsA, tid);         // fresh h_L0 -> hsA (also P1(t+1)'s h)
      __syncthreads();
      lstm_phase<false>(tid, bid, nullptr, nullptr, hsA, hsB,
                        Wih + (size_t)2048 * Hz, Whh + (size_t)2048 * Hz,
                        bih + 2048, bhh + 2048, s_part, s_bias, s_c + 128,
                        hbufs + BHz);
    } else if (bid == 128) {
      for (int u = tid; u < 2048; u += NTz) {
        __hip_atomic_store(&acc_sum[u], 0.f, __ATOMIC_RELAXED, __HIP_MEMORY_SCOPE_AGENT);
        __hip_atomic_store(&acc_max[u], 0ull, __ATOMIC_RELAXED, __HIP_MEMORY_SCOPE_AGENT);
      }
    }
    grid_barrier(bar, bid, ++bcnt);

    //---- P3: stage fresh h_L1 -> hsB; register matvec; softmax partials ----
    stage_rows(hbufs + BHz, hsB, tid);
    __syncthreads();
    {
      #pragma unroll 2
      for (int b = 0; b < 32; ++b) {
        const float* hb = hsB + (b << 9);
        const int swz = (b & 15) << 2;
        f32x4 acc4[4];
        #pragma unroll
        for (int r = 0; r < 4; ++r) acc4[r] = (f32x4)0.f;
        #pragma unroll
        for (int j = 0; j < 8; ++j) {
          const int k = (kq << 5) + (((j + kq) & 7) << 2);
          f32x4 hv = *(const f32x4*)(hb + (k ^ swz));
          #pragma unroll
          for (int r = 0; r < 4; ++r) acc4[r] += hv * w4[r][j];
        }
        #pragma unroll
        for (int r = 0; r < 4; ++r) {
          float a = (acc4[r].x + acc4[r].y) + (acc4[r].z + acc4[r].w);
          a += __shfl_xor(a, 1);
          a += __shfl_xor(a, 2);
          a += __shfl_xor(a, 4);
          a += __shfl_xor(a, 8);
          if (kq == 0) logits[b * 129 + (vg << 2) + r] = a + b_r[r];
        }
      }
    }
    __syncthreads();
    {
      const int b2 = tid & 31, ch = tid >> 5;   // 16 chunks x 8 vocab
      float m = -3.0e38f; int argv = 0; float s = 0.f;
      #pragma unroll
      for (int u = 0; u < 8; ++u) {
        int vl = ch * 8 + u;
        float x = logits[b2 * 129 + vl];
        s += expf(x);                            // offset-0 softmax: logits are O(1), safe
        if (x > m) { m = x; argv = vl; }
      }
      pmax[ch * 32 + b2] = packlm(m, v0 + argv);
      psum[ch * 32 + b2] = s;
    }
    __syncthreads();
    if (tid < 32) {
      ull m = 0ull; float s = 0.f;
      #pragma unroll
      for (int ch = 0; ch < 16; ++ch) {
        ull x = pmax[ch * 32 + tid]; m = x > m ? x : m;
        s += psum[ch * 32 + tid];
      }
      atomicAdd(&acc_sum[(bid & 63) * Bz + tid], s);
      atomicMax(&acc_max[(bid & 63) * Bz + tid], m);
    }
    grid_barrier(bar, bid, ++bcnt);
  }

  //---- epilogue: logp(T-1), hT, cT ----
  tok_reduce(tid, acc_sum, acc_max, redS, redM, s_logZ, s_tok);
  write_logp(tid, v0, Tz - 1, logits, s_logZ, out);
  if (bid >= 128 && bid < 144) {
    int f = (bid - 128) * 2048 + tid * 4;       // hT: 32768 floats
    ull a = bp8(hbufs + f), b = bp8(hbufs + f + 2);
    *(ull*)(out + BTVz + f) = a;
    *(ull*)(out + BTVz + f + 2) = b;
  }
  if (bid < 128 && tid < 256) {
    int l = tid >> 7, hl = (tid >> 5) & 3, bb = tid & 31;
    out[BTVz + LBHz + (size_t)l * BHz + (size_t)bb * Hz + (bid << 2) + hl] =
        s_c[l * 128 + hl * 32 + bb];
  }
}

extern "C" void kernel_launch(void* const* d_in, const int* in_sizes, int n_in,
                              void* d_out, int out_size, void* d_ws, size_t ws_size,
                              hipStream_t stream) {
  (void)in_sizes; (void)n_in; (void)out_size; (void)ws_size;
  const float* enc  = (const float*)d_in[0];
  const float* emb  = (const float*)d_in[1];
  const float* Wih  = (const float*)d_in[2];
  const float* Whh  = (const float*)d_in[3];
  const float* bih  = (const float*)d_in[4];
  const float* bhh  = (const float*)d_in[5];
  const float* Wout = (const float*)d_in[6];
  const float* bout = (const float*)d_in[7];
  float* out = (float*)d_out;
  float* ws  = (float*)d_ws;

  (void)hipFuncSetAttribute((const void*)rnn_decode,
                            hipFuncAttributeMaxDynamicSharedMemorySize, L_TOTAL);
  rnn_init<<<64, 512, 0, stream>>>(enc, ws);
  rnn_decode<<<Gz, NTz, L_TOTAL, stream>>>(emb, Wih, Whh, bih, bhh, Wout, bout, out, ws);
}